// Round 3
// baseline (939.157 us; speedup 1.0000x reference)
//
#include <hip/hip_runtime.h>
#include <hip/hip_cooperative_groups.h>
#include <cstdint>
#include <math.h>

namespace cg = cooperative_groups;

#define H 1024
#define V 50257
#define NBLK 1024   // cooperative grid: 4 blocks/CU x 256 CU
#define NTHR 256

__device__ __forceinline__ float dot4(float4 a, float4 b) {
    return a.x * b.x + a.y * b.y + a.z * b.z + a.w * b.w;
}

// Block computes output element i of one GRU layer: 6 H-dots + gates.
__device__ __forceinline__ void gru_elem(
    int i, int t, float4 xv,
    const float* __restrict__ hprev,
    const float* __restrict__ Wih, const float* __restrict__ Whh,
    const float* __restrict__ bih, const float* __restrict__ bhh,
    float* __restrict__ hnew_ws, float* __restrict__ hnew_out,
    float (&red)[4][6])
{
    float s[6];
    {
        const float* r0 = Wih + (size_t)i * H;
        const float* r1 = Wih + (size_t)(H + i) * H;
        const float* r2 = Wih + (size_t)(2 * H + i) * H;
        const float* r3 = Whh + (size_t)i * H;
        const float* r4 = Whh + (size_t)(H + i) * H;
        const float* r5 = Whh + (size_t)(2 * H + i) * H;
        float4 hv = *(const float4*)(hprev + 4 * t);
        s[0] = dot4(*(const float4*)(r0 + 4 * t), xv);
        s[1] = dot4(*(const float4*)(r1 + 4 * t), xv);
        s[2] = dot4(*(const float4*)(r2 + 4 * t), xv);
        s[3] = dot4(*(const float4*)(r3 + 4 * t), hv);
        s[4] = dot4(*(const float4*)(r4 + 4 * t), hv);
        s[5] = dot4(*(const float4*)(r5 + 4 * t), hv);
    }
    #pragma unroll
    for (int m = 1; m < 64; m <<= 1) {
        #pragma unroll
        for (int k = 0; k < 6; ++k) s[k] += __shfl_xor(s[k], m);
    }
    const int wv = t >> 6, ln = t & 63;
    if (ln == 0) {
        #pragma unroll
        for (int k = 0; k < 6; ++k) red[wv][k] = s[k];
    }
    __syncthreads();
    if (t == 0) {
        float g[6];
        #pragma unroll
        for (int k = 0; k < 6; ++k)
            g[k] = red[0][k] + red[1][k] + red[2][k] + red[3][k];
        float gir = g[0] + bih[i], giz = g[1] + bih[H + i], gin = g[2] + bih[2 * H + i];
        float ghr = g[3] + bhh[i], ghz = g[4] + bhh[H + i], ghn = g[5] + bhh[2 * H + i];
        float r = 1.f / (1.f + expf(-(gir + ghr)));
        float z = 1.f / (1.f + expf(-(giz + ghz)));
        float n = tanhf(gin + r * ghn);
        float hp = hprev[i];
        float hn = (1.f - z) * n + z * hp;
        hnew_ws[i] = hn;
        hnew_out[i] = hn;
    }
    __syncthreads();   // red[] reused by next stage
}

// ---------------- fused cooperative kernel ----------------
__global__ __launch_bounds__(NTHR, 4) void fused_kernel(
    const int* __restrict__ tok, const float* __restrict__ hidden,
    const float* __restrict__ emb,
    const float* __restrict__ Wih, const float* __restrict__ Whh,
    const float* __restrict__ bih, const float* __restrict__ bhh,
    const float* __restrict__ Wout, const float* __restrict__ bout,
    float* __restrict__ out, float* __restrict__ ws)
{
    cg::grid_group grid = cg::this_grid();
    __shared__ float red[4][6];
    __shared__ float smax[4], ssum[4], slz;

    float* pmax = ws;                // [0, NBLK)
    float* psum = ws + NBLK;         // [NBLK, 2*NBLK)
    float* h0   = ws + 2 * NBLK;     // H
    float* h1   = h0 + H;            // H

    const int t = threadIdx.x, b = blockIdx.x;
    const int wv = t >> 6, ln = t & 63;

    // ---- stage 0: GRU layer 0, x = relu(emb[tok]) ----
    {
        const float* xb = emb + (size_t)tok[0] * (size_t)H;
        float4 xv = *(const float4*)(xb + 4 * t);
        xv.x = fmaxf(xv.x, 0.f); xv.y = fmaxf(xv.y, 0.f);
        xv.z = fmaxf(xv.z, 0.f); xv.w = fmaxf(xv.w, 0.f);
        gru_elem(b, t, xv, hidden, Wih, Whh, bih, bhh, h0, out + V, red);
    }
    __threadfence();
    grid.sync();

    // ---- stage 1: GRU layer 1, x = h0 ----
    {
        float4 xv = *(const float4*)(h0 + 4 * t);
        gru_elem(b, t, xv, hidden + H, Wih + 3 * H * H, Whh + 3 * H * H,
                 bih + 3 * H, bhh + 3 * H, h1, out + V + H, red);
    }
    __threadfence();
    grid.sync();

    // ---- stage 2: projection, wave-per-row, online logsumexp ----
    {
        float4 hr[4];
        #pragma unroll
        for (int j = 0; j < 4; ++j) hr[j] = *(const float4*)(h1 + 4 * (ln + 64 * j));

        const int gw = b * 4 + wv;
        const int nw = NBLK * 4;
        float wmax = -INFINITY, wsum = 0.f;
        for (int v = gw; v < V; v += nw) {
            const float* wrow = Wout + (size_t)v * H;
            float s = 0.f;
            #pragma unroll
            for (int j = 0; j < 4; ++j)
                s += dot4(*(const float4*)(wrow + 4 * (ln + 64 * j)), hr[j]);
            #pragma unroll
            for (int m = 1; m < 64; m <<= 1) s += __shfl_xor(s, m);
            s += bout[v];
            if (ln == 0) out[v] = s;
            float nm = fmaxf(wmax, s);
            wsum = wsum * expf(wmax - nm) + expf(s - nm);
            wmax = nm;
        }
        if (ln == 0) { smax[wv] = wmax; ssum[wv] = wsum; }
        __syncthreads();
        if (t == 0) {
            float m = fmaxf(fmaxf(smax[0], smax[1]), fmaxf(smax[2], smax[3]));
            float su = 0.f;
            #pragma unroll
            for (int w = 0; w < 4; ++w) su += ssum[w] * expf(smax[w] - m);
            pmax[b] = m;
            psum[b] = su;
        }
    }
    __threadfence();
    grid.sync();

    // ---- stage 3: reduce partials (redundant per block), subtract logZ ----
    {
        float m = -INFINITY, su = 0.f;
        for (int i = t; i < NBLK; i += NTHR) {
            float om = pmax[i], os = psum[i];
            float nm = fmaxf(m, om);
            su = su * expf(m - nm) + os * expf(om - nm);
            m = nm;
        }
        #pragma unroll
        for (int k = 1; k < 64; k <<= 1) {
            float om = __shfl_xor(m, k), os = __shfl_xor(su, k);
            float nm = fmaxf(m, om);
            su = su * expf(m - nm) + os * expf(om - nm);
            m = nm;
        }
        if (ln == 0) { smax[wv] = m; ssum[wv] = su; }
        __syncthreads();
        if (t == 0) {
            float mm = fmaxf(fmaxf(smax[0], smax[1]), fmaxf(smax[2], smax[3]));
            float ss = 0.f;
            #pragma unroll
            for (int w = 0; w < 4; ++w) ss += ssum[w] * expf(smax[w] - mm);
            slz = mm + logf(ss);
        }
        __syncthreads();
        const float lz = slz;
        for (int v = b * NTHR + t; v < V; v += NBLK * NTHR)
            out[v] = out[v] - lz;
    }
}

// ---------------- fallback path (proven 4-kernel version) ----------------
__global__ __launch_bounds__(256) void gru_layer(
    const float* __restrict__ emb, const int* __restrict__ tok, int use_emb,
    const float* __restrict__ xvec, const float* __restrict__ hprev,
    const float* __restrict__ Wih, const float* __restrict__ Whh,
    const float* __restrict__ bih, const float* __restrict__ bhh,
    float* __restrict__ hnew_ws, float* __restrict__ hnew_out)
{
    __shared__ float red[4][6];
    const int i = blockIdx.x, t = threadIdx.x;
    const float* xb = use_emb ? (emb + (size_t)tok[0] * (size_t)H) : xvec;
    float4 xv = *(const float4*)(xb + 4 * t);
    if (use_emb) {
        xv.x = fmaxf(xv.x, 0.f); xv.y = fmaxf(xv.y, 0.f);
        xv.z = fmaxf(xv.z, 0.f); xv.w = fmaxf(xv.w, 0.f);
    }
    gru_elem(i, t, xv, hprev, Wih, Whh, bih, bhh, hnew_ws, hnew_out, red);
}

__global__ __launch_bounds__(256) void proj_kernel(
    const float* __restrict__ h, const float* __restrict__ Wout,
    const float* __restrict__ bout, float* __restrict__ logits,
    float* __restrict__ pmax, float* __restrict__ psum)
{
    const int t = threadIdx.x, wv = t >> 6, ln = t & 63;
    const int gw = blockIdx.x * 4 + wv, nw = NBLK * 4;
    float4 hr[4];
    #pragma unroll
    for (int j = 0; j < 4; ++j) hr[j] = *(const float4*)(h + 4 * (ln + 64 * j));
    float wmax = -INFINITY, wsum = 0.f;
    for (int v = gw; v < V; v += nw) {
        const float* wrow = Wout + (size_t)v * H;
        float s = 0.f;
        #pragma unroll
        for (int j = 0; j < 4; ++j)
            s += dot4(*(const float4*)(wrow + 4 * (ln + 64 * j)), hr[j]);
        #pragma unroll
        for (int m = 1; m < 64; m <<= 1) s += __shfl_xor(s, m);
        s += bout[v];
        if (ln == 0) logits[v] = s;
        float nm = fmaxf(wmax, s);
        wsum = wsum * expf(wmax - nm) + expf(s - nm);
        wmax = nm;
    }
    __shared__ float smax[4], ssum[4];
    if (ln == 0) { smax[wv] = wmax; ssum[wv] = wsum; }
    __syncthreads();
    if (t == 0) {
        float m = fmaxf(fmaxf(smax[0], smax[1]), fmaxf(smax[2], smax[3]));
        float su = 0.f;
        #pragma unroll
        for (int w = 0; w < 4; ++w) su += ssum[w] * expf(smax[w] - m);
        pmax[blockIdx.x] = m;
        psum[blockIdx.x] = su;
    }
}

__global__ __launch_bounds__(256) void finalize_kernel(
    float* __restrict__ logits,
    const float* __restrict__ pmax, const float* __restrict__ psum)
{
    const int t = threadIdx.x;
    float m = -INFINITY, su = 0.f;
    for (int i = t; i < NBLK; i += 256) {
        float om = pmax[i], os = psum[i];
        float nm = fmaxf(m, om);
        su = su * expf(m - nm) + os * expf(om - nm);
        m = nm;
    }
    #pragma unroll
    for (int k = 1; k < 64; k <<= 1) {
        float om = __shfl_xor(m, k), os = __shfl_xor(su, k);
        float nm = fmaxf(m, om);
        su = su * expf(m - nm) + os * expf(om - nm);
        m = nm;
    }
    __shared__ float smax[4], ssum[4], slz;
    if ((t & 63) == 0) { smax[t >> 6] = m; ssum[t >> 6] = su; }
    __syncthreads();
    if (t == 0) {
        float mm = fmaxf(fmaxf(smax[0], smax[1]), fmaxf(smax[2], smax[3]));
        float ss = 0.f;
        #pragma unroll
        for (int w = 0; w < 4; ++w) ss += ssum[w] * expf(smax[w] - mm);
        slz = mm + logf(ss);
    }
    __syncthreads();
    const float lz = slz;
    for (int v = blockIdx.x * 256 + t; v < V; v += gridDim.x * 256)
        logits[v] = logits[v] - lz;
}

extern "C" void kernel_launch(void* const* d_in, const int* in_sizes, int n_in,
                              void* d_out, int out_size, void* d_ws, size_t ws_size,
                              hipStream_t stream) {
    const int*   tok    = (const int*)d_in[0];     // low 32 bits of int64 (LE)
    const float* hidden = (const float*)d_in[1];   // (2,1,H)
    const float* emb    = (const float*)d_in[2];   // (V,H)
    const float* Wih    = (const float*)d_in[3];   // (2,3H,H)
    const float* Whh    = (const float*)d_in[4];
    const float* bih    = (const float*)d_in[5];   // (2,3H)
    const float* bhh    = (const float*)d_in[6];
    const float* Wout   = (const float*)d_in[7];   // (V,H)
    const float* bout   = (const float*)d_in[8];   // (V,)

    float* out = (float*)d_out;        // [0,V): logprobs; [V,V+2H): hidden_new
    float* ws  = (float*)d_ws;

    void* args[] = {(void*)&tok, (void*)&hidden, (void*)&emb,
                    (void*)&Wih, (void*)&Whh, (void*)&bih, (void*)&bhh,
                    (void*)&Wout, (void*)&bout, (void*)&out, (void*)&ws};
    hipError_t err = hipLaunchCooperativeKernel(
        (const void*)fused_kernel, dim3(NBLK), dim3(NTHR), args, 0, stream);

    if (err != hipSuccess) {
        // fallback: proven 4-kernel path
        float* pmax = ws;
        float* psum = ws + NBLK;
        float* h0 = ws + 2 * NBLK;
        float* h1 = h0 + H;
        gru_layer<<<H, 256, 0, stream>>>(emb, tok, 1, nullptr, hidden,
                                         Wih, Whh, bih, bhh, h0, out + V);
        gru_layer<<<H, 256, 0, stream>>>(nullptr, nullptr, 0, h0, hidden + H,
                                         Wih + 3 * H * H, Whh + 3 * H * H,
                                         bih + 3 * H, bhh + 3 * H, h1, out + V + H);
        proj_kernel<<<NBLK, 256, 0, stream>>>(h1, Wout, bout, out, pmax, psum);
        finalize_kernel<<<256, 256, 0, stream>>>(out, pmax, psum);
    }
}

// Round 4
// 852.040 us; speedup vs baseline: 1.1022x; 1.1022x over previous
//
#include <hip/hip_runtime.h>
#include <cstdint>
#include <math.h>

#define H 1024
#define V 50257
#define NBLK 1024
#define NW 4096            // waves in proj grid (NBLK*4)
#define MAGIC 0x13579BDFu  // != 0xAAAAAAAA poison

typedef unsigned int u32;
typedef unsigned long long u64;

__device__ __forceinline__ float dot4(float4 a, float4 b) {
    return a.x * b.x + a.y * b.y + a.z * b.z + a.w * b.w;
}
__device__ __forceinline__ void st_rel_u32(u32* p, u32 v) {
    __hip_atomic_store(p, v, __ATOMIC_RELEASE, __HIP_MEMORY_SCOPE_AGENT);
}
__device__ __forceinline__ u32 ld_acq_u32(const u32* p) {
    return __hip_atomic_load(p, __ATOMIC_ACQUIRE, __HIP_MEMORY_SCOPE_AGENT);
}
__device__ __forceinline__ u64 ld_rlx_u64(const u64* p) {
    return __hip_atomic_load(p, __ATOMIC_RELAXED, __HIP_MEMORY_SCOPE_AGENT);
}

// One GRU layer, output element i, 256 threads. Returns h_new (valid on t==0).
__device__ __forceinline__ float gru_half(
    int i, int t, float4 xv, const float* __restrict__ hprev,
    const float* __restrict__ Wih, const float* __restrict__ Whh,
    const float* __restrict__ bih, const float* __restrict__ bhh,
    float (&red)[4][6])
{
    float s[6];
    {
        const float* r0 = Wih + (size_t)i * H;
        const float* r1 = Wih + (size_t)(H + i) * H;
        const float* r2 = Wih + (size_t)(2 * H + i) * H;
        const float* r3 = Whh + (size_t)i * H;
        const float* r4 = Whh + (size_t)(H + i) * H;
        const float* r5 = Whh + (size_t)(2 * H + i) * H;
        float4 hv = *(const float4*)(hprev + 4 * t);
        s[0] = dot4(*(const float4*)(r0 + 4 * t), xv);
        s[1] = dot4(*(const float4*)(r1 + 4 * t), xv);
        s[2] = dot4(*(const float4*)(r2 + 4 * t), xv);
        s[3] = dot4(*(const float4*)(r3 + 4 * t), hv);
        s[4] = dot4(*(const float4*)(r4 + 4 * t), hv);
        s[5] = dot4(*(const float4*)(r5 + 4 * t), hv);
    }
    #pragma unroll
    for (int m = 1; m < 64; m <<= 1) {
        #pragma unroll
        for (int k = 0; k < 6; ++k) s[k] += __shfl_xor(s[k], m);
    }
    const int wv = t >> 6, ln = t & 63;
    if (ln == 0) {
        #pragma unroll
        for (int k = 0; k < 6; ++k) red[wv][k] = s[k];
    }
    __syncthreads();
    float hn = 0.f;
    if (t == 0) {
        float g[6];
        #pragma unroll
        for (int k = 0; k < 6; ++k)
            g[k] = red[0][k] + red[1][k] + red[2][k] + red[3][k];
        float gir = g[0] + bih[i], giz = g[1] + bih[H + i], gin = g[2] + bih[2 * H + i];
        float ghr = g[3] + bhh[i], ghz = g[4] + bhh[H + i], ghn = g[5] + bhh[2 * H + i];
        float r = 1.f / (1.f + expf(-(gir + ghr)));
        float z = 1.f / (1.f + expf(-(giz + ghz)));
        float n = tanhf(gin + r * ghn);
        float hp = hprev[i];
        hn = (1.f - z) * n + z * hp;
    }
    __syncthreads();   // red[] reused by caller's next phase
    return hn;
}

// Kernel 1: both GRU layers, rendezvous between them via agent-scope flags.
// 1024 blocks @ <=64 VGPR -> 4/CU needed vs 8/CU capacity (2x margin).
__global__ __launch_bounds__(256, 8) void gru2_fused(
    const int* __restrict__ tok, const float* __restrict__ hidden,
    const float* __restrict__ emb,
    const float* __restrict__ Wih, const float* __restrict__ Whh,
    const float* __restrict__ bih, const float* __restrict__ bhh,
    float* __restrict__ out, u32* __restrict__ h0_bits,
    float* __restrict__ h1, u32* __restrict__ gflag)
{
    const int b = blockIdx.x, t = threadIdx.x;
    __shared__ float red[4][6];

    // ---- phase A: layer 0, x = relu(emb[tok]) ----
    {
        const float* xb = emb + (size_t)tok[0] * (size_t)H;
        float4 xv = *(const float4*)(xb + 4 * t);
        xv.x = fmaxf(xv.x, 0.f); xv.y = fmaxf(xv.y, 0.f);
        xv.z = fmaxf(xv.z, 0.f); xv.w = fmaxf(xv.w, 0.f);
        float h0v = gru_half(b, t, xv, hidden, Wih, Whh, bih, bhh, red);
        if (t == 0) {
            out[V + b] = h0v;                                  // hidden_new[0]
            st_rel_u32(&h0_bits[b], __float_as_uint(h0v));     // release data
            st_rel_u32(&gflag[b], MAGIC);                      // then flag
        }
    }
    // ---- rendezvous: wait for all h0 elements ----
    for (int k = t; k < NBLK; k += 256)
        while (ld_acq_u32(&gflag[k]) != MAGIC) __builtin_amdgcn_s_sleep(2);
    __syncthreads();
    // ---- phase B: layer 1, x = h0 (agent-scope 8B loads, bit-exact) ----
    {
        u64 w0 = ld_rlx_u64((const u64*)h0_bits + 2 * t);
        u64 w1 = ld_rlx_u64((const u64*)h0_bits + 2 * t + 1);
        float4 xv = make_float4(__uint_as_float((u32)w0),
                                __uint_as_float((u32)(w0 >> 32)),
                                __uint_as_float((u32)w1),
                                __uint_as_float((u32)(w1 >> 32)));
        float h1v = gru_half(b, t, xv, hidden + H,
                             Wih + 3 * H * H, Whh + 3 * H * H,
                             bih + 3 * H, bhh + 3 * H, red);
        if (t == 0) {
            out[V + H + b] = h1v;    // hidden_new[1]
            h1[b] = h1v;             // for proj (cross-kernel, plain store ok)
        }
    }
}

// Kernel 2: projection + online logsumexp + rendezvous + in-kernel logZ subtract.
__global__ __launch_bounds__(256, 8) void proj_fused(
    const float* __restrict__ h, const float* __restrict__ Wout,
    const float* __restrict__ bout, float* __restrict__ out,
    u32* __restrict__ part_bits,   // [2b]=max bits, [2b+1]=sum bits
    u32* __restrict__ pflag)
{
    const int b = blockIdx.x, t = threadIdx.x;
    const int wv = t >> 6, ln = t & 63;
    const int gw = b * 4 + wv;

    float4 hr[4];
    #pragma unroll
    for (int j = 0; j < 4; ++j) hr[j] = *(const float4*)(h + 4 * (ln + 64 * j));

    float wmax = -INFINITY, wsum = 0.f;
    for (int v = gw; v < V; v += NW) {
        const float* wrow = Wout + (size_t)v * H;
        float s = 0.f;
        #pragma unroll
        for (int j = 0; j < 4; ++j)
            s += dot4(*(const float4*)(wrow + 4 * (ln + 64 * j)), hr[j]);
        #pragma unroll
        for (int m = 1; m < 64; m <<= 1) s += __shfl_xor(s, m);
        s += bout[v];
        if (ln == 0) out[v] = s;
        float nm = fmaxf(wmax, s);
        wsum = wsum * expf(wmax - nm) + expf(s - nm);
        wmax = nm;
    }
    __shared__ float smax[4], ssum[4], slz;
    if (ln == 0) { smax[wv] = wmax; ssum[wv] = wsum; }
    __syncthreads();
    if (t == 0) {
        float m = fmaxf(fmaxf(smax[0], smax[1]), fmaxf(smax[2], smax[3]));
        float su = 0.f;
        #pragma unroll
        for (int w = 0; w < 4; ++w) su += ssum[w] * expf(smax[w] - m);
        st_rel_u32(&part_bits[2 * b], __float_as_uint(m));
        st_rel_u32(&part_bits[2 * b + 1], __float_as_uint(su));
        st_rel_u32(&pflag[b], MAGIC);
    }
    // ---- rendezvous: wait for all block partials ----
    for (int k = t; k < NBLK; k += 256)
        while (ld_acq_u32(&pflag[k]) != MAGIC) __builtin_amdgcn_s_sleep(2);
    __syncthreads();
    // ---- redundant reduce of 1024 partials -> logZ ----
    {
        float m = -INFINITY, su = 0.f;
        for (int i = t; i < NBLK; i += 256) {
            u64 w = ld_rlx_u64((const u64*)part_bits + i);
            float om = __uint_as_float((u32)w);
            float os = __uint_as_float((u32)(w >> 32));
            float nm = fmaxf(m, om);
            su = su * expf(m - nm) + os * expf(om - nm);
            m = nm;
        }
        #pragma unroll
        for (int k = 1; k < 64; k <<= 1) {
            float om = __shfl_xor(m, k), os = __shfl_xor(su, k);
            float nm = fmaxf(m, om);
            su = su * expf(m - nm) + os * expf(om - nm);
            m = nm;
        }
        if (ln == 0) { smax[wv] = m; ssum[wv] = su; }
        __syncthreads();
        if (t == 0) {
            float mm = fmaxf(fmaxf(smax[0], smax[1]), fmaxf(smax[2], smax[3]));
            float ss = 0.f;
            #pragma unroll
            for (int w = 0; w < 4; ++w) ss += ssum[w] * expf(smax[w] - mm);
            slz = mm + logf(ss);
        }
        __syncthreads();
    }
    // ---- subtract logZ from this wave's OWN rows (stay in own XCD L2) ----
    {
        const float lz = slz;
        if (gw < V) {
            int nr = (V - 1 - gw) / NW + 1;   // 12 or 13 rows
            if (ln < nr) {
                int v = gw + ln * NW;
                out[v] = out[v] - lz;
            }
        }
    }
}

extern "C" void kernel_launch(void* const* d_in, const int* in_sizes, int n_in,
                              void* d_out, int out_size, void* d_ws, size_t ws_size,
                              hipStream_t stream) {
    const int*   tok    = (const int*)d_in[0];     // low 32 bits of int64 (LE)
    const float* hidden = (const float*)d_in[1];   // (2,1,H)
    const float* emb    = (const float*)d_in[2];   // (V,H)
    const float* Wih    = (const float*)d_in[3];   // (2,3H,H)
    const float* Whh    = (const float*)d_in[4];
    const float* bih    = (const float*)d_in[5];   // (2,3H)
    const float* bhh    = (const float*)d_in[6];
    const float* Wout   = (const float*)d_in[7];   // (V,H)
    const float* bout   = (const float*)d_in[8];   // (V,)

    float* out = (float*)d_out;        // [0,V): logprobs; [V,V+2H): hidden_new
    u32*   ws  = (u32*)d_ws;
    u32*   h0_bits   = ws;             // [0, 1024)
    float* h1        = (float*)(ws + 1024);   // [1024, 2048)
    u32*   part_bits = ws + 2048;      // [2048, 4096)
    u32*   gflag     = ws + 4096;      // [4096, 5120)
    u32*   pflag     = ws + 5120;      // [5120, 6144)

    gru2_fused<<<NBLK, 256, 0, stream>>>(tok, hidden, emb, Wih, Whh, bih, bhh,
                                         out, h0_bits, h1, gflag);
    proj_fused<<<NBLK, 256, 0, stream>>>(h1, Wout, bout, out, part_bits, pflag);
}